// Round 1
// baseline (55.316 us; speedup 1.0000x reference)
//
#include <hip/hip_runtime.h>
#include <math.h>

// Problem constants (from reference)
#define NB   64
#define CIN  3
#define HH   512
#define WW   384
#define PP   16      // pooled rows
#define QQ   12      // pooled cols
// pool block = 32x32; strip = 32 rows x 384 cols = 12288 floats, contiguous.

// ---------------------------------------------------------------------------
// Kernel 1: 32x32 average pooling.
// grid = N*C*P = 3072 strips; block = 384 threads.
// Each strip is a contiguous chunk of 12288 floats (3072 float4).
// thread t: col4 = t%96 (96 float4 per row), row-group rg = t/96 (stride 4).
// ---------------------------------------------------------------------------
__global__ __launch_bounds__(384)
void pool_kernel(const float* __restrict__ x, float* __restrict__ pooled)
{
    const int sb = blockIdx.x;            // ((n*C + c)*P + p)
    const int t  = threadIdx.x;
    const int col4 = t % 96;
    const int rg   = t / 96;

    const float4* base = reinterpret_cast<const float4*>(x) + (size_t)sb * 3072;

    float sum = 0.f;
#pragma unroll
    for (int r = rg; r < 32; r += 4) {
        float4 v = base[r * 96 + col4];
        sum += (v.x + v.y) + (v.z + v.w);
    }

    __shared__ float part[384];
    part[t] = sum;
    __syncthreads();

    if (t < QQ) {
        float tot = 0.f;
#pragma unroll
        for (int g = 0; g < 4; ++g) {
#pragma unroll
            for (int j = 0; j < 8; ++j)
                tot += part[g * 96 + t * 8 + j];
        }
        pooled[sb * QQ + t] = tot * (1.0f / 1024.0f);
    }
}

// ---------------------------------------------------------------------------
// Kernel 2: threshold -> gate -> fold (algebraic form) -> projection.
// grid = N (64 blocks); block = 512 threads (one per output feature).
//
// folded[c][i][j] = thr[c][i][j] * G[i][j],
//   G[i][j] = sum of gate[oh][ow] over windows covering padded pos (i+1,j+1)
//   gate[oh][ow] = sigmoid( (10/27) * sum_{c,kh,kw} padthr[c][2oh+kh][2ow+kw] )
// ---------------------------------------------------------------------------
__global__ __launch_bounds__(512)
void head_kernel(const float* __restrict__ pooled,
                 const float* __restrict__ Wt,     // (576, 512) row-major
                 const float* __restrict__ bias,   // (512)
                 float* __restrict__ out)          // (N, 512)
{
    const int n = blockIdx.x;
    const int t = threadIdx.x;

    __shared__ float thr[576];   // [c][i][j] = c*192 + i*12 + j
    __shared__ float gate[48];   // [oh][ow]  = oh*6 + ow
    __shared__ float Gs[192];    // [i][j]
    __shared__ float f[576];     // folded, flattened

    for (int k = t; k < 576; k += 512) {
        float p = pooled[n * 576 + k];
        thr[k] = (p > 0.05f) ? p : 0.f;
    }
    __syncthreads();

    if (t < 48) {
        const int oh = t / 6, ow = t % 6;
        float S = 0.f;
#pragma unroll
        for (int c = 0; c < 3; ++c)
#pragma unroll
            for (int kh = 0; kh < 3; ++kh)
#pragma unroll
                for (int kw = 0; kw < 3; ++kw) {
                    int r = oh * 2 + kh - 1;   // unpadded row
                    int s = ow * 2 + kw - 1;   // unpadded col
                    if (r >= 0 && r < PP && s >= 0 && s < QQ)
                        S += thr[c * 192 + r * 12 + s];
                }
        gate[t] = 1.f / (1.f + expf(-S * (10.0f / 27.0f)));
    }
    __syncthreads();

    if (t < 192) {
        const int i = t / 12, j = t % 12;
        const int r = i + 1, s = j + 1;        // padded coords
        float g = 0.f;
#pragma unroll
        for (int kh = 0; kh < 3; ++kh) {
            int oh2 = r - kh;
            if (oh2 < 0 || (oh2 & 1) || (oh2 >> 1) >= 8) continue;
            int oh = oh2 >> 1;
#pragma unroll
            for (int kw = 0; kw < 3; ++kw) {
                int ow2 = s - kw;
                if (ow2 < 0 || (ow2 & 1) || (ow2 >> 1) >= 6) continue;
                g += gate[oh * 6 + (ow2 >> 1)];
            }
        }
        Gs[t] = g;
    }
    __syncthreads();

    for (int k = t; k < 576; k += 512)
        f[k] = thr[k] * Gs[k % 192];
    __syncthreads();

    // out[n][t] = bias[t] + sum_k f[k] * Wt[k*512 + t]
    float acc = bias[t];
#pragma unroll 8
    for (int k = 0; k < 576; ++k)
        acc = fmaf(f[k], Wt[k * 512 + t], acc);
    out[n * 512 + t] = acc;
}

// ---------------------------------------------------------------------------
extern "C" void kernel_launch(void* const* d_in, const int* in_sizes, int n_in,
                              void* d_out, int out_size, void* d_ws, size_t ws_size,
                              hipStream_t stream)
{
    const float* x    = (const float*)d_in[0];   // (64,3,512,384) f32
    const float* Wt   = (const float*)d_in[1];   // (576,512) f32
    const float* bias = (const float*)d_in[2];   // (512,) f32
    float* out = (float*)d_out;                  // (64,512) f32
    float* pooled = (float*)d_ws;                // 64*3*16*12 = 36864 floats

    pool_kernel<<<NB * CIN * PP, 384, 0, stream>>>(x, pooled);
    head_kernel<<<NB, 512, 0, stream>>>(pooled, Wt, bias, out);
}

// Round 2
// 51.005 us; speedup vs baseline: 1.0845x; 1.0845x over previous
//
#include <hip/hip_runtime.h>
#include <math.h>

// Problem constants (from reference)
#define NB   64
#define CIN  3
#define HH   512
#define WW   384
#define PP   16      // pooled rows
#define QQ   12      // pooled cols

// ---------------------------------------------------------------------------
// Kernel 1: 32x32 average pooling.
// grid = N*C*P = 3072 strips; block = 384 threads.
// Each strip is a contiguous chunk of 12288 floats (3072 float4).
// thread t: col4 = t%96 (96 float4 per row), row-group rg = t/96 (stride 4).
// ---------------------------------------------------------------------------
__global__ __launch_bounds__(384)
void pool_kernel(const float* __restrict__ x, float* __restrict__ pooled)
{
    const int sb = blockIdx.x;            // ((n*C + c)*P + p)
    const int t  = threadIdx.x;
    const int col4 = t % 96;
    const int rg   = t / 96;

    const float4* base = reinterpret_cast<const float4*>(x) + (size_t)sb * 3072;

    float sum = 0.f;
#pragma unroll
    for (int r = rg; r < 32; r += 4) {
        float4 v = base[r * 96 + col4];
        sum += (v.x + v.y) + (v.z + v.w);
    }

    __shared__ float part[384];
    part[t] = sum;
    __syncthreads();

    // stage 1: fold the 4 row-groups (96 threads)
    if (t < 96) {
        part[t] = (part[t] + part[96 + t]) + (part[192 + t] + part[288 + t]);
    }
    __syncthreads();

    // stage 2: 12 q-sums of 8 col4-partials each
    if (t < QQ) {
        float tot = 0.f;
#pragma unroll
        for (int j = 0; j < 8; ++j)
            tot += part[t * 8 + j];
        pooled[sb * QQ + t] = tot * (1.0f / 1024.0f);
    }
}

// ---------------------------------------------------------------------------
// Kernel 2: threshold -> gate -> fold (algebraic form) -> projection.
// grid = 16 sample-groups x 8 feature-chunks = 128 blocks; block = 256 thr.
// Wave w of a block handles sample ng*4+w; lane l handles feature jc*64+l.
// All 4 waves read identical W addresses -> L1 broadcast reuse.
//
// folded[c][i][j] = thr[c][i][j] * G[i][j],
//   G[i][j] = sum of gate[oh][ow] over windows covering padded pos (i+1,j+1)
//   gate[oh][ow] = sigmoid( (10/27) * sum_{c,kh,kw} padthr[c][2oh+kh][2ow+kw] )
// ---------------------------------------------------------------------------
__global__ __launch_bounds__(256)
void head_kernel(const float* __restrict__ pooled,
                 const float* __restrict__ Wt,     // (576, 512) row-major
                 const float* __restrict__ bias,   // (512)
                 float* __restrict__ out)          // (N, 512)
{
    const int blk = blockIdx.x;      // 0..127
    const int ng  = blk >> 3;        // sample group 0..15 (4 samples each)
    const int jc  = blk & 7;         // feature chunk 0..7 (64 features each)
    const int t   = threadIdx.x;
    const int w   = t >> 6;          // wave id 0..3 -> sample ng*4+w
    const int l   = t & 63;          // lane -> feature jc*64+l

    __shared__ float thr[4][576];    // [s][c*192 + i*12 + j]
    __shared__ float gate[4][48];    // [s][oh*6 + ow]
    __shared__ float f[4][576];      // folded, flattened

    // threshold (4 samples x 576)
    for (int k = t; k < 4 * 576; k += 256) {
        int s = k / 576, kk = k - s * 576;
        float p = pooled[(ng * 4 + s) * 576 + kk];
        thr[s][kk] = (p > 0.05f) ? p : 0.f;
    }
    __syncthreads();

    // gate (4 x 48 = 192 items)
    if (t < 192) {
        int s = t / 48, g = t - s * 48;
        int oh = g / 6, ow = g - oh * 6;
        float S = 0.f;
#pragma unroll
        for (int c = 0; c < 3; ++c)
#pragma unroll
            for (int kh = 0; kh < 3; ++kh)
#pragma unroll
                for (int kw = 0; kw < 3; ++kw) {
                    int r  = oh * 2 + kh - 1;   // unpadded row
                    int sx = ow * 2 + kw - 1;   // unpadded col
                    if (r >= 0 && r < PP && sx >= 0 && sx < QQ)
                        S += thr[s][c * 192 + r * 12 + sx];
                }
        gate[s][g] = 1.f / (1.f + expf(-S * (10.0f / 27.0f)));
    }
    __syncthreads();

    // f = thr * G  (4 x 576), G recomputed per (i,j)
    for (int k = t; k < 4 * 576; k += 256) {
        int s = k / 576, kk = k - s * 576;
        int ij = kk % 192;
        int i = ij / 12, j = ij - i * 12;
        int r = i + 1, sx = j + 1;             // padded coords
        float g = 0.f;
#pragma unroll
        for (int kh = 0; kh < 3; ++kh) {
            int oh2 = r - kh;
            if (oh2 < 0 || (oh2 & 1) || (oh2 >> 1) >= 8) continue;
            int oh = oh2 >> 1;
#pragma unroll
            for (int kw = 0; kw < 3; ++kw) {
                int ow2 = sx - kw;
                if (ow2 < 0 || (ow2 & 1) || (ow2 >> 1) >= 6) continue;
                g += gate[s][oh * 6 + (ow2 >> 1)];
            }
        }
        f[s][kk] = thr[s][kk] * g;
    }
    __syncthreads();

    // projection: out[n][j] = bias[j] + sum_k f[w][k] * Wt[k*512 + j]
    const int j = jc * 64 + l;
    const int n = ng * 4 + w;
    const float* Wp = Wt + j;
    float a0 = 0.f, a1 = 0.f, a2 = 0.f, a3 = 0.f;
#pragma unroll 4
    for (int k = 0; k < 576; k += 4) {
        a0 = fmaf(f[w][k + 0], Wp[(size_t)(k + 0) * 512], a0);
        a1 = fmaf(f[w][k + 1], Wp[(size_t)(k + 1) * 512], a1);
        a2 = fmaf(f[w][k + 2], Wp[(size_t)(k + 2) * 512], a2);
        a3 = fmaf(f[w][k + 3], Wp[(size_t)(k + 3) * 512], a3);
    }
    out[n * 512 + j] = bias[j] + (a0 + a1) + (a2 + a3);
}

// ---------------------------------------------------------------------------
extern "C" void kernel_launch(void* const* d_in, const int* in_sizes, int n_in,
                              void* d_out, int out_size, void* d_ws, size_t ws_size,
                              hipStream_t stream)
{
    const float* x    = (const float*)d_in[0];   // (64,3,512,384) f32
    const float* Wt   = (const float*)d_in[1];   // (576,512) f32
    const float* bias = (const float*)d_in[2];   // (512,) f32
    float* out = (float*)d_out;                  // (64,512) f32
    float* pooled = (float*)d_ws;                // 64*3*16*12 = 36864 floats

    pool_kernel<<<NB * CIN * PP, 384, 0, stream>>>(x, pooled);
    head_kernel<<<16 * 8, 256, 0, stream>>>(pooled, Wt, bias, out);
}

// Round 3
// 34.116 us; speedup vs baseline: 1.6214x; 1.4950x over previous
//
#include <hip/hip_runtime.h>
#include <math.h>

// Problem constants (from reference)
#define NB   64
#define CIN  3
#define HH   512
#define WW   384
#define PP   16      // pooled rows
#define QQ   12      // pooled cols

// ---------------------------------------------------------------------------
// Kernel 1: 32x32 average pooling.
// grid = N*C*P = 3072 strips; block = 384 threads.
// Each strip is a contiguous chunk of 12288 floats (3072 float4).
// thread t: col4 = t%96 (96 float4 per row), row-group rg = t/96 (stride 4).
// ---------------------------------------------------------------------------
__global__ __launch_bounds__(384)
void pool_kernel(const float* __restrict__ x, float* __restrict__ pooled)
{
    const int sb = blockIdx.x;            // ((n*C + c)*P + p)
    const int t  = threadIdx.x;
    const int col4 = t % 96;
    const int rg   = t / 96;

    const float4* base = reinterpret_cast<const float4*>(x) + (size_t)sb * 3072;

    float sum = 0.f;
#pragma unroll
    for (int r = rg; r < 32; r += 4) {
        float4 v = base[r * 96 + col4];
        sum += (v.x + v.y) + (v.z + v.w);
    }

    __shared__ float part[384];
    part[t] = sum;
    __syncthreads();

    // stage 1: fold the 4 row-groups (96 threads)
    if (t < 96) {
        part[t] = (part[t] + part[96 + t]) + (part[192 + t] + part[288 + t]);
    }
    __syncthreads();

    // stage 2: 12 q-sums of 8 col4-partials each
    if (t < QQ) {
        float tot = 0.f;
#pragma unroll
        for (int j = 0; j < 8; ++j)
            tot += part[t * 8 + j];
        pooled[sb * QQ + t] = tot * (1.0f / 1024.0f);
    }
}

// ---------------------------------------------------------------------------
// Kernel 2: threshold -> gate -> fold (algebraic form) -> projection.
// grid = 64 samples x 8 feature-chunks = 512 blocks; block = 512 threads.
// Thread t: l = t&63 -> feature j = jc*64+l; kc = t>>6 -> k in [kc*72,kc*72+72).
// 2 blocks/CU -> 4 waves/SIMD; k-split 8x cuts serial load-latency chain 8x.
//
// folded[c][i][j] = thr[c][i][j] * G[i][j],
//   G[i][j] = sum of gate[oh][ow] over windows covering padded pos (i+1,j+1)
//   gate[oh][ow] = sigmoid( (10/27) * sum_{c,kh,kw} padthr[c][2oh+kh][2ow+kw] )
// ---------------------------------------------------------------------------
__global__ __launch_bounds__(512)
void head_kernel(const float* __restrict__ pooled,
                 const float* __restrict__ Wt,     // (576, 512) row-major
                 const float* __restrict__ bias,   // (512)
                 float* __restrict__ out)          // (N, 512)
{
    const int blk = blockIdx.x;      // 0..511
    const int n   = blk >> 3;        // sample 0..63
    const int jc  = blk & 7;         // feature chunk 0..7 (64 features each)
    const int t   = threadIdx.x;
    const int l   = t & 63;          // lane -> feature jc*64+l
    const int kc  = t >> 6;          // k-chunk 0..7

    __shared__ float thr[576];       // [c*192 + i*12 + j]
    __shared__ float gate[48];       // [oh*6 + ow]
    __shared__ float f[576];         // folded, flattened
    __shared__ float part[512];      // projection partials [kc*64 + l]

    // threshold (576)
    for (int k = t; k < 576; k += 512) {
        float p = pooled[n * 576 + k];
        thr[k] = (p > 0.05f) ? p : 0.f;
    }
    __syncthreads();

    // gate (48 items)
    if (t < 48) {
        int oh = t / 6, ow = t - oh * 6;
        float S = 0.f;
#pragma unroll
        for (int c = 0; c < 3; ++c)
#pragma unroll
            for (int kh = 0; kh < 3; ++kh)
#pragma unroll
                for (int kw = 0; kw < 3; ++kw) {
                    int r  = oh * 2 + kh - 1;   // unpadded row
                    int sx = ow * 2 + kw - 1;   // unpadded col
                    if (r >= 0 && r < PP && sx >= 0 && sx < QQ)
                        S += thr[c * 192 + r * 12 + sx];
                }
        gate[t] = 1.f / (1.f + expf(-S * (10.0f / 27.0f)));
    }
    __syncthreads();

    // f = thr * G  (576), G recomputed per (i,j)
    for (int k = t; k < 576; k += 512) {
        int ij = k % 192;
        int i = ij / 12, j = ij - i * 12;
        int r = i + 1, sx = j + 1;             // padded coords
        float g = 0.f;
#pragma unroll
        for (int kh = 0; kh < 3; ++kh) {
            int oh2 = r - kh;
            if (oh2 < 0 || (oh2 & 1) || (oh2 >> 1) >= 8) continue;
            int oh = oh2 >> 1;
#pragma unroll
            for (int kw = 0; kw < 3; ++kw) {
                int ow2 = sx - kw;
                if (ow2 < 0 || (ow2 & 1) || (ow2 >> 1) >= 6) continue;
                g += gate[oh * 6 + (ow2 >> 1)];
            }
        }
        f[k] = thr[k] * g;
    }
    __syncthreads();

    // projection partial: part[kc*64+l] = sum_{k in chunk} f[k] * Wt[k*512+j]
    const int j  = jc * 64 + l;
    const int k0 = kc * 72;
    const float* Wp = Wt + (size_t)k0 * 512 + j;
    float a0 = 0.f, a1 = 0.f, a2 = 0.f, a3 = 0.f;
#pragma unroll 6
    for (int kk = 0; kk < 72; kk += 4) {
        a0 = fmaf(f[k0 + kk + 0], Wp[(size_t)(kk + 0) * 512], a0);
        a1 = fmaf(f[k0 + kk + 1], Wp[(size_t)(kk + 1) * 512], a1);
        a2 = fmaf(f[k0 + kk + 2], Wp[(size_t)(kk + 2) * 512], a2);
        a3 = fmaf(f[k0 + kk + 3], Wp[(size_t)(kk + 3) * 512], a3);
    }
    part[t] = (a0 + a1) + (a2 + a3);
    __syncthreads();

    // reduce 8 k-chunks per feature
    if (t < 64) {
        float acc = bias[j];
#pragma unroll
        for (int c = 0; c < 8; ++c)
            acc += part[c * 64 + t];
        out[n * 512 + j] = acc;
    }
}

// ---------------------------------------------------------------------------
extern "C" void kernel_launch(void* const* d_in, const int* in_sizes, int n_in,
                              void* d_out, int out_size, void* d_ws, size_t ws_size,
                              hipStream_t stream)
{
    const float* x    = (const float*)d_in[0];   // (64,3,512,384) f32
    const float* Wt   = (const float*)d_in[1];   // (576,512) f32
    const float* bias = (const float*)d_in[2];   // (512,) f32
    float* out = (float*)d_out;                  // (64,512) f32
    float* pooled = (float*)d_ws;                // 64*3*16*12 = 36864 floats

    pool_kernel<<<NB * CIN * PP, 384, 0, stream>>>(x, pooled);
    head_kernel<<<NB * 8, 512, 0, stream>>>(pooled, Wt, bias, out);
}